// Round 5
// baseline (402.761 us; speedup 1.0000x reference)
//
#include <hip/hip_runtime.h>
#include <hip/hip_bf16.h>

#define BS 2
#define QLEN 2048
#define DIM 2048
#define H 16
#define DH 128
#define MTOT (BS*QLEN)

#define BM 256
#define BN 128
#define BK 64
#define NT (DIM/BK)   // 32 K-tiles

typedef __hip_bfloat16 bf16;
using f32x4 = __attribute__((ext_vector_type(4))) float;
using s16x8 = __attribute__((ext_vector_type(8))) short;

__device__ inline void gload_lds16(const bf16* g, bf16* l) {
    __builtin_amdgcn_global_load_lds(
        (const __attribute__((address_space(1))) void*)g,
        (__attribute__((address_space(3))) void*)l,
        16, 0, 0);
}

// ---------------- fp32 -> bf16 cast: 6 slices in one dispatch ----------------
__global__ __launch_bounds__(256) void cast6(
    const float* __restrict__ x,
    const float* __restrict__ w0, const float* __restrict__ w1,
    const float* __restrict__ w2, const float* __restrict__ w3,
    bf16* xo, bf16* o0, bf16* o1, bf16* o2, bf16* o3, int n4)
{
    const float* in; bf16* out;
    switch (blockIdx.y) {
        case 0:  in = w0; out = o0; break;
        case 1:  in = w1; out = o1; break;
        case 2:  in = w2; out = o2; break;
        case 3:  in = w3; out = o3; break;
        case 4:  in = x;        out = xo;        break;
        default: in = x + 4*(size_t)n4; out = xo + 4*(size_t)n4; break;
    }
    int i = blockIdx.x * 256 + threadIdx.x;
    if (i < n4) {
        float4 v = ((const float4*)in)[i];
        __hip_bfloat162 p0 = __float22bfloat162_rn(make_float2(v.x, v.y));
        __hip_bfloat162 p1 = __float22bfloat162_rn(make_float2(v.z, v.w));
        ((__hip_bfloat162*)out)[2*i]   = p0;
        ((__hip_bfloat162*)out)[2*i+1] = p1;
    }
}

// ---------------- Q/K projection GEMM: 256x256 tile, wave-tile 128x64 ----------------
__global__ __launch_bounds__(512, 2) void gemm_qk(
    const bf16* __restrict__ A,
    const bf16* __restrict__ Wq, const bf16* __restrict__ Wk,
    const float* __restrict__ bq, const float* __restrict__ bk,
    bf16* __restrict__ Qo, bf16* __restrict__ Ko,
    float qscale)
{
    __shared__ __align__(16) bf16 smem[2*256*64*2];   // 128 KB
    bf16* const SA = smem;
    bf16* const SB = smem + 2*256*64;

    const int t = threadIdx.x;
    const int lane = t & 63, w = t >> 6;
    const int row16 = lane & 15, quad = lane >> 4;

    const int sid = (blockIdx.z * 16 + blockIdx.y) * 8 + blockIdx.x;
    const int swz = (sid & 7) * 32 + (sid >> 3);
    const int zz = swz >> 7;                 // 0: Q, 1: K
    const int m0 = ((swz >> 3) & 15) * 256;
    const int n0 = (swz & 7) * 256;
    const int mo = (w >> 2) * 128, no = (w & 3) * 64;

    const bf16*  Bw   = (zz == 0) ? Wq : Wk;
    const float* bias = (zz == 0) ? bq : bk;
    const float  scale = (zz == 0) ? qscale : 1.0f;

    auto stageA_part = [&](int kt, int bufi, int h) {
        bf16* dst = SA + bufi * (256*64);
        #pragma unroll
        for (int i = 0; i < 2; i++) {
            int c = i*512 + t;
            int rp = c >> 3, g = c & 7;
            int row = (rp & 63) + ((rp & 64) << 1) + h*64;
            int src = g ^ (row & 7);
            gload_lds16(A + (size_t)(m0 + row) * DIM + kt + src*8, dst + (row*8 + g)*8);
        }
    };
    auto stageB_half = [&](int kt, int bufi, int h) {
        bf16* dst = SB + bufi * (256*64);
        #pragma unroll
        for (int i = 0; i < 2; i++) {
            int c = i*512 + t;
            int rp = c >> 3, g = c & 7;
            int row = rp + h*128;
            int src = g ^ (row & 7);
            gload_lds16(Bw + (size_t)(n0 + row) * DIM + kt + src*8, dst + (row*8 + g)*8);
        }
    };

    f32x4 acc[8][4];
    #pragma unroll
    for (int i = 0; i < 8; i++)
        #pragma unroll
        for (int j = 0; j < 4; j++)
            acc[i][j] = (f32x4){0.f, 0.f, 0.f, 0.f};

    stageB_half(0, 0, 0); stageB_half(0, 0, 1);
    stageA_part(0, 0, 0); stageA_part(0, 0, 1);
    asm volatile("s_waitcnt vmcnt(0)" ::: "memory");
    __builtin_amdgcn_s_barrier();
    asm volatile("" ::: "memory");

    for (int J = 0; J < NT; ++J) {
        const bf16* Asb = SA + (J & 1) * (256*64);
        const bf16* Bsb = SB + (J & 1) * (256*64);
        const int stbuf = (J + 1) & 1;
        const bool st = (J + 1 < NT);
        s16x8 bfr[4][2];

        #pragma unroll
        for (int p = 0; p < 4; ++p) {
            s16x8 af[2][2];
            #pragma unroll
            for (int i = 0; i < 2; i++)
                #pragma unroll
                for (int kk = 0; kk < 2; kk++)
                    af[i][kk] = *(const s16x8*)&Asb[(mo + (2*p+i)*16 + row16)*64 +
                                                    (((kk*4+quad) ^ (row16&7)))*8];
            if (p == 0) {
                #pragma unroll
                for (int nj = 0; nj < 4; nj++)
                    #pragma unroll
                    for (int kk = 0; kk < 2; kk++)
                        bfr[nj][kk] = *(const s16x8*)&Bsb[(no + nj*16 + row16)*64 +
                                                          (((kk*4+quad) ^ (row16&7)))*8];
            }
            if (st) {
                if      (p == 0) stageB_half((J+1)*BK, stbuf, 0);
                else if (p == 1) stageB_half((J+1)*BK, stbuf, 1);
                else if (p == 2) stageA_part((J+1)*BK, stbuf, 0);
                else             stageA_part((J+1)*BK, stbuf, 1);
            }
            if (p == 1) {
                if (J < NT-1) asm volatile("s_waitcnt vmcnt(4)" ::: "memory");
                else          asm volatile("s_waitcnt vmcnt(0)" ::: "memory");
            }
            if (p == 3 && J < NT-1)
                asm volatile("s_waitcnt vmcnt(2)" ::: "memory");

            asm volatile("" ::: "memory");
            __builtin_amdgcn_s_barrier();
            asm volatile("s_waitcnt lgkmcnt(0)" ::: "memory");
            __builtin_amdgcn_sched_barrier(0);
            __builtin_amdgcn_s_setprio(1);
            #pragma unroll
            for (int kk = 0; kk < 2; kk++)
                #pragma unroll
                for (int i = 0; i < 2; i++)
                    #pragma unroll
                    for (int nj = 0; nj < 4; nj++)
                        acc[2*p+i][nj] = __builtin_amdgcn_mfma_f32_16x16x32_bf16(
                            af[i][kk], bfr[nj][kk], acc[2*p+i][nj], 0, 0, 0);
            __builtin_amdgcn_s_setprio(0);
            if (!(p == 3 && J == NT-1)) {
                asm volatile("" ::: "memory");
                __builtin_amdgcn_s_barrier();
                asm volatile("" ::: "memory");
            }
        }
    }

    bf16* out = (zz == 0) ? Qo : Ko;
    #pragma unroll
    for (int mi = 0; mi < 8; mi++)
        #pragma unroll
        for (int nj = 0; nj < 4; nj++) {
            int n = n0 + no + nj*16 + row16;
            float bv_ = bias[n];
            #pragma unroll
            for (int r = 0; r < 4; r++) {
                int m = m0 + mo + mi*16 + quad*4 + r;
                out[(size_t)m * DIM + n] = __float2bfloat16((acc[mi][nj][r] + bv_) * scale);
            }
        }
}

// ---------------- V projection GEMM (2-phase, V-transposed out) ----------------
__global__ __launch_bounds__(512, 2) void gemm_v(
    const bf16* __restrict__ A, const bf16* __restrict__ B,
    const float* __restrict__ bias, bf16* __restrict__ Vo)
{
    __shared__ __align__(16) bf16 smem[3*BM*BK + 3*BN*BK];
    bf16* const SA = smem;
    bf16* const SB = smem + 3*BM*BK;

    const int t = threadIdx.x;
    const int lane = t & 63, w = t >> 6;
    const int row16 = lane & 15, quad = lane >> 4;
    const int sid = blockIdx.y * gridDim.x + blockIdx.x;
    const int swz = (sid & 7) * 32 + (sid >> 3);
    const int m0 = (swz >> 4) * BM, n0 = (swz & 15) * BN;
    const int mo = (w >> 1) * 64, no = (w & 1) * 64;

    auto stageA = [&](int kt, int bufi) {
        bf16* dst = SA + bufi * (BM*BK);
        #pragma unroll
        for (int i = 0; i < 4; i++) {
            int idx = i*512 + t;
            int row = idx >> 3, g = idx & 7;
            int src = g ^ (row & 7);
            gload_lds16(A + (size_t)(m0 + row) * DIM + kt + src*8, dst + idx*8);
        }
    };
    auto stageB = [&](int kt, int bufi) {
        bf16* dst = SB + bufi * (BN*BK);
        #pragma unroll
        for (int i = 0; i < 2; i++) {
            int idx = i*512 + t;
            int row = idx >> 3, g = idx & 7;
            int src = g ^ (row & 7);
            gload_lds16(B + (size_t)(n0 + row) * DIM + kt + src*8, dst + idx*8);
        }
    };

    f32x4 acc[4][4];
    for (int i = 0; i < 4; i++)
        for (int j = 0; j < 4; j++)
            acc[i][j] = (f32x4){0.f, 0.f, 0.f, 0.f};

    stageA(0,    0); stageB(0,    0);
    stageA(BK,   1); stageB(BK,   1);
    stageA(2*BK, 2); stageB(2*BK, 2);
    asm volatile("s_waitcnt vmcnt(12)" ::: "memory");
    __builtin_amdgcn_s_barrier();
    asm volatile("" ::: "memory");

    int buf = 0;
    for (int J = 0; J < NT; ++J) {
        const bf16* Asb = SA + buf * (BM*BK);
        const bf16* Bsb = SB + buf * (BN*BK);

        s16x8 af0[4], bf0[4];
        #pragma unroll
        for (int mt = 0; mt < 4; mt++)
            af0[mt] = *(const s16x8*)&Asb[(mo + mt*16 + row16)*BK + ((quad ^ (row16&7)))*8];
        #pragma unroll
        for (int nt = 0; nt < 4; nt++)
            bf0[nt] = *(const s16x8*)&Bsb[(no + nt*16 + row16)*BK + ((quad ^ (row16&7)))*8];
        if (J >= 1 && J + 2 < NT) {
            int sl = (buf == 0) ? 2 : buf - 1;
            stageA((J+2)*BK, sl); stageB((J+2)*BK, sl);
        }
        asm volatile("" ::: "memory");
        __builtin_amdgcn_s_barrier();
        asm volatile("s_waitcnt lgkmcnt(0)" ::: "memory");
        __builtin_amdgcn_sched_barrier(0);
        __builtin_amdgcn_s_setprio(1);
        #pragma unroll
        for (int mt = 0; mt < 4; mt++)
            #pragma unroll
            for (int nt = 0; nt < 4; nt++)
                acc[mt][nt] = __builtin_amdgcn_mfma_f32_16x16x32_bf16(
                    af0[mt], bf0[nt], acc[mt][nt], 0, 0, 0);
        __builtin_amdgcn_s_setprio(0);
        asm volatile("" ::: "memory");
        __builtin_amdgcn_s_barrier();
        asm volatile("" ::: "memory");

        s16x8 af1[4], bf1[4];
        #pragma unroll
        for (int mt = 0; mt < 4; mt++)
            af1[mt] = *(const s16x8*)&Asb[(mo + mt*16 + row16)*BK + (((4+quad) ^ (row16&7)))*8];
        #pragma unroll
        for (int nt = 0; nt < 4; nt++)
            bf1[nt] = *(const s16x8*)&Bsb[(no + nt*16 + row16)*BK + (((4+quad) ^ (row16&7)))*8];
        asm volatile("" ::: "memory");
        __builtin_amdgcn_s_barrier();
        asm volatile("s_waitcnt lgkmcnt(0)" ::: "memory");
        __builtin_amdgcn_sched_barrier(0);
        __builtin_amdgcn_s_setprio(1);
        #pragma unroll
        for (int mt = 0; mt < 4; mt++)
            #pragma unroll
            for (int nt = 0; nt < 4; nt++)
                acc[mt][nt] = __builtin_amdgcn_mfma_f32_16x16x32_bf16(
                    af1[mt], bf1[nt], acc[mt][nt], 0, 0, 0);
        __builtin_amdgcn_s_setprio(0);
        if (J < NT-2)
            asm volatile("s_waitcnt vmcnt(6)" ::: "memory");
        else if (J == NT-2)
            asm volatile("s_waitcnt vmcnt(0)" ::: "memory");
        if (J < NT-1) {
            asm volatile("" ::: "memory");
            __builtin_amdgcn_s_barrier();
            asm volatile("" ::: "memory");
        }
        buf = (buf == 2) ? 0 : buf + 1;
    }

    __syncthreads();
    bf16* Ts = smem;                 // 128 x 264
    for (int mt = 0; mt < 4; mt++)
        for (int nt = 0; nt < 4; nt++) {
            int nn = no + nt*16 + row16;
            float bv_ = bias[n0 + nn];
            for (int r = 0; r < 4; r++) {
                int mm = mo + mt*16 + quad*4 + r;
                Ts[nn*264 + mm] = __float2bfloat16(acc[mt][nt][r] + bv_);
            }
        }
    __syncthreads();
    const int b = m0 >> 11, q0b = m0 & 2047;
    #pragma unroll
    for (int i = 0; i < 8; i++) {
        int chunk = i*512 + t;
        int row = chunk >> 5;
        int c = chunk & 31;
        s16x8 val = *(const s16x8*)&Ts[row*264 + c*8];
        *(s16x8*)(Vo + ((size_t)(b*DIM + n0 + row))*QLEN + q0b + c*8) = val;
    }
}

// ---------------- O-projection GEMM (2-phase), fp32 out ----------------
__global__ __launch_bounds__(512, 2) void gemm_out(
    const bf16* __restrict__ A, const bf16* __restrict__ B,
    const float* __restrict__ bias, float* __restrict__ out)
{
    __shared__ __align__(16) bf16 smem[3*BM*BK + 3*BN*BK];
    bf16* const SA = smem;
    bf16* const SB = smem + 3*BM*BK;

    const int t = threadIdx.x;
    const int lane = t & 63, w = t >> 6;
    const int row16 = lane & 15, quad = lane >> 4;
    const int sid = blockIdx.y * gridDim.x + blockIdx.x;
    const int swz = (sid & 7) * 32 + (sid >> 3);
    const int m0 = (swz >> 4) * BM, n0 = (swz & 15) * BN;
    const int mo = (w >> 1) * 64, no = (w & 1) * 64;

    auto stageA = [&](int kt, int bufi) {
        bf16* dst = SA + bufi * (BM*BK);
        #pragma unroll
        for (int i = 0; i < 4; i++) {
            int idx = i*512 + t;
            int row = idx >> 3, g = idx & 7;
            int src = g ^ (row & 7);
            gload_lds16(A + (size_t)(m0 + row) * DIM + kt + src*8, dst + idx*8);
        }
    };
    auto stageB = [&](int kt, int bufi) {
        bf16* dst = SB + bufi * (BN*BK);
        #pragma unroll
        for (int i = 0; i < 2; i++) {
            int idx = i*512 + t;
            int row = idx >> 3, g = idx & 7;
            int src = g ^ (row & 7);
            gload_lds16(B + (size_t)(n0 + row) * DIM + kt + src*8, dst + idx*8);
        }
    };

    f32x4 acc[4][4];
    for (int i = 0; i < 4; i++)
        for (int j = 0; j < 4; j++)
            acc[i][j] = (f32x4){0.f, 0.f, 0.f, 0.f};

    stageA(0,    0); stageB(0,    0);
    stageA(BK,   1); stageB(BK,   1);
    stageA(2*BK, 2); stageB(2*BK, 2);
    asm volatile("s_waitcnt vmcnt(12)" ::: "memory");
    __builtin_amdgcn_s_barrier();
    asm volatile("" ::: "memory");

    int buf = 0;
    for (int J = 0; J < NT; ++J) {
        const bf16* Asb = SA + buf * (BM*BK);
        const bf16* Bsb = SB + buf * (BN*BK);

        s16x8 af0[4], bf0[4];
        #pragma unroll
        for (int mt = 0; mt < 4; mt++)
            af0[mt] = *(const s16x8*)&Asb[(mo + mt*16 + row16)*BK + ((quad ^ (row16&7)))*8];
        #pragma unroll
        for (int nt = 0; nt < 4; nt++)
            bf0[nt] = *(const s16x8*)&Bsb[(no + nt*16 + row16)*BK + ((quad ^ (row16&7)))*8];
        if (J >= 1 && J + 2 < NT) {
            int sl = (buf == 0) ? 2 : buf - 1;
            stageA((J+2)*BK, sl); stageB((J+2)*BK, sl);
        }
        asm volatile("" ::: "memory");
        __builtin_amdgcn_s_barrier();
        asm volatile("s_waitcnt lgkmcnt(0)" ::: "memory");
        __builtin_amdgcn_sched_barrier(0);
        __builtin_amdgcn_s_setprio(1);
        #pragma unroll
        for (int mt = 0; mt < 4; mt++)
            #pragma unroll
            for (int nt = 0; nt < 4; nt++)
                acc[mt][nt] = __builtin_amdgcn_mfma_f32_16x16x32_bf16(
                    af0[mt], bf0[nt], acc[mt][nt], 0, 0, 0);
        __builtin_amdgcn_s_setprio(0);
        asm volatile("" ::: "memory");
        __builtin_amdgcn_s_barrier();
        asm volatile("" ::: "memory");

        s16x8 af1[4], bf1[4];
        #pragma unroll
        for (int mt = 0; mt < 4; mt++)
            af1[mt] = *(const s16x8*)&Asb[(mo + mt*16 + row16)*BK + (((4+quad) ^ (row16&7)))*8];
        #pragma unroll
        for (int nt = 0; nt < 4; nt++)
            bf1[nt] = *(const s16x8*)&Bsb[(no + nt*16 + row16)*BK + (((4+quad) ^ (row16&7)))*8];
        asm volatile("" ::: "memory");
        __builtin_amdgcn_s_barrier();
        asm volatile("s_waitcnt lgkmcnt(0)" ::: "memory");
        __builtin_amdgcn_sched_barrier(0);
        __builtin_amdgcn_s_setprio(1);
        #pragma unroll
        for (int mt = 0; mt < 4; mt++)
            #pragma unroll
            for (int nt = 0; nt < 4; nt++)
                acc[mt][nt] = __builtin_amdgcn_mfma_f32_16x16x32_bf16(
                    af1[mt], bf1[nt], acc[mt][nt], 0, 0, 0);
        __builtin_amdgcn_s_setprio(0);
        if (J < NT-2)
            asm volatile("s_waitcnt vmcnt(6)" ::: "memory");
        else if (J == NT-2)
            asm volatile("s_waitcnt vmcnt(0)" ::: "memory");
        if (J < NT-1) {
            asm volatile("" ::: "memory");
            __builtin_amdgcn_s_barrier();
            asm volatile("" ::: "memory");
        }
        buf = (buf == 2) ? 0 : buf + 1;
    }

    for (int mt = 0; mt < 4; mt++)
        for (int nt = 0; nt < 4; nt++) {
            int n = n0 + no + nt*16 + row16;
            float bv_ = bias[n];
            for (int r = 0; r < 4; r++) {
                int m = m0 + mo + mt*16 + quad*4 + r;
                out[(size_t)m * DIM + n] = acc[mt][nt][r] + bv_;
            }
        }
}

// ---------------- flash attention: QBLK=64, 4 blocks/CU, counted-vmcnt ----------------
// 4 waves x 16 q-rows. LDS 40KB: Ks 16K (single) + Vs 16K + Pl 8K -> 4 blocks/CU.
// Per tile: [bar][issue V][vmcnt(4): K ready][bar][QK+softmax][lgkm0,vmcnt(0)][bar]
//           [issue K(it+1)][PV]. K(it+1) lands during PV + next top barrier.
__global__ __launch_bounds__(256, 4) void attn(
    const bf16* __restrict__ Q, const bf16* __restrict__ Kb,
    const bf16* __restrict__ Vt, const int* __restrict__ mask,
    bf16* __restrict__ Ctx)
{
    __shared__ __align__(16) bf16 Ks[64*128];    // 16 KB
    __shared__ __align__(16) bf16 Vs[128*64];    // 16 KB
    __shared__ __align__(16) bf16 Pl[4][16*64];  // 8 KB (swizzled)

    const int t = threadIdx.x, w = t >> 6, lane = t & 63;
    const int row16 = lane & 15, quad = lane >> 4;
    // XCD swizzle: 1024 blocks, 128/XCD = 4 bh-groups x 32 q-tiles intact
    const int sid = blockIdx.y * gridDim.x + blockIdx.x;
    const int swz = (sid & 7) * 128 + (sid >> 3);
    const int bh = swz >> 5, b = bh >> 4, h = bh & 15;
    const int q0 = (swz & 31) * 64 + w * 16;

    s16x8 qf[4];
    {
        const bf16* qp = Q + (size_t)(b*QLEN + q0 + row16) * DIM + h*DH;
        #pragma unroll
        for (int ks = 0; ks < 4; ks++)
            qf[ks] = *(const s16x8*)(qp + ks*32 + quad*8);
    }

    f32x4 o[8];
    #pragma unroll
    for (int i = 0; i < 8; i++) o[i] = (f32x4){0.f, 0.f, 0.f, 0.f};
    float lsum[4] = {0.f, 0.f, 0.f, 0.f};
    const int* mrow = mask + b * QLEN;

    const bf16* Kbase = Kb + (size_t)b*QLEN*DIM + h*DH;
    const bf16* Vbase = Vt + ((size_t)b*DIM + h*DH) * QLEN;

    auto stageK = [&](int kt) {
        #pragma unroll
        for (int i = 0; i < 4; i++) {
            int idx = i*256 + t;
            int kr = idx >> 4, kc = idx & 15;
            int kg = kc ^ (kr & 15);
            gload_lds16(Kbase + (size_t)(kt + kr) * DIM + kg*8, &Ks[idx*8]);
        }
    };
    auto stageV = [&](int kt) {
        #pragma unroll
        for (int i = 0; i < 4; i++) {
            int idx = i*256 + t;
            int vd = idx >> 3, vc = idx & 7;
            int vg = vc ^ (vd & 7);
            gload_lds16(Vbase + (size_t)vd * QLEN + kt + vg*8, &Vs[idx*8]);
        }
    };

    stageK(0);   // prologue

    for (int it = 0; it < QLEN/64; it++) {
        const int kt = it * 64;

        // ---- top barrier: all waves done PV(it-1) -> Vs safe to overwrite ----
        asm volatile("" ::: "memory");
        __builtin_amdgcn_s_barrier();
        asm volatile("" ::: "memory");

        stageV(kt);                                         // V(it) in flight
        asm volatile("s_waitcnt vmcnt(4)" ::: "memory");    // K(it) landed (V newest 4)
        __builtin_amdgcn_s_barrier();                       // all waves' K landed
        asm volatile("" ::: "memory");

        float mval[4];
        #pragma unroll
        for (int nt = 0; nt < 4; nt++)
            mval[nt] = (mrow[kt + nt*16 + row16] != 0) ? -20.0f : -1e30f;

        // ---- scores ----
        f32x4 sc[4];
        #pragma unroll
        for (int nt = 0; nt < 4; nt++) sc[nt] = (f32x4){0.f, 0.f, 0.f, 0.f};
        __builtin_amdgcn_s_setprio(1);
        #pragma unroll
        for (int ks = 0; ks < 4; ks++) {
            #pragma unroll
            for (int nt = 0; nt < 4; nt++) {
                int rrow = nt*16 + row16;
                int c = (ks*4 + quad) ^ row16;
                s16x8 kf = *(const s16x8*)&Ks[rrow*128 + c*8];
                sc[nt] = __builtin_amdgcn_mfma_f32_16x16x32_bf16(qf[ks], kf, sc[nt], 0, 0, 0);
            }
        }
        __builtin_amdgcn_s_setprio(0);

        // ---- softmax numerator: p = exp2(s - 20) -> Pl (swizzled) ----
        #pragma unroll
        for (int r = 0; r < 4; r++) {
            int prow = quad*4 + r;
            float ts = 0.f;
            #pragma unroll
            for (int nt = 0; nt < 4; nt++) {
                float p = exp2f(sc[nt][r] + mval[nt]);
                ts += p;
                int chunk = nt*2 + (row16 >> 3);
                int slot = chunk ^ (prow & 7);
                Pl[w][prow*64 + slot*8 + (row16 & 7)] = __float2bfloat16(p);
            }
            lsum[r] += ts;
        }

        asm volatile("s_waitcnt lgkmcnt(0)" ::: "memory");  // own Pl writes done
        asm volatile("s_waitcnt vmcnt(0)" ::: "memory");    // V(it) landed
        __builtin_amdgcn_s_barrier();                       // all waves: V ready, QK reads done
        asm volatile("" ::: "memory");

        if (it + 1 < QLEN/64)
            stageK(kt + 64);                                // lands during PV + next top bar

        // ---- PV ----
        __builtin_amdgcn_s_setprio(1);
        #pragma unroll
        for (int kc = 0; kc < 2; kc++) {
            int pslot0 = ((kc*4 + quad) ^ (row16 & 7));
            s16x8 pf = *(const s16x8*)&Pl[w][row16*64 + pslot0*8];
            #pragma unroll
            for (int nt = 0; nt < 8; nt++) {
                int d = nt*16 + row16;
                int c = (kc*4 + quad) ^ (d & 7);
                s16x8 vf = *(const s16x8*)&Vs[d*64 + c*8];
                o[nt] = __builtin_amdgcn_mfma_f32_16x16x32_bf16(pf, vf, o[nt], 0, 0, 0);
            }
        }
        __builtin_amdgcn_s_setprio(0);
    }

    float inv[4];
    #pragma unroll
    for (int r = 0; r < 4; r++) {
        float ts = lsum[r];
        ts += __shfl_xor(ts, 1);
        ts += __shfl_xor(ts, 2);
        ts += __shfl_xor(ts, 4);
        ts += __shfl_xor(ts, 8);
        inv[r] = 1.0f / ts;
    }
    #pragma unroll
    for (int nt = 0; nt < 8; nt++)
        #pragma unroll
        for (int r = 0; r < 4; r++) {
            float v = o[nt][r] * inv[r];
            Ctx[(size_t)(b*QLEN + q0 + quad*4 + r) * DIM + h*DH + nt*16 + row16] =
                __float2bfloat16(v);
        }
}

extern "C" void kernel_launch(void* const* d_in, const int* in_sizes, int n_in,
                              void* d_out, int out_size, void* d_ws, size_t ws_size,
                              hipStream_t stream) {
    const float* x    = (const float*)d_in[0];
    const int*   mask = (const int*)d_in[1];
    const float* wq   = (const float*)d_in[2];
    const float* bq   = (const float*)d_in[3];
    const float* wk   = (const float*)d_in[4];
    const float* bk   = (const float*)d_in[5];
    const float* wv   = (const float*)d_in[6];
    const float* bv   = (const float*)d_in[7];
    const float* wo   = (const float*)d_in[8];
    const float* bo   = (const float*)d_in[9];

    char* ws = (char*)d_ws;
    const size_t MB = 1024 * 1024;
    bf16* Xb  = (bf16*)(ws);             // 16MB, later reused as Ctx
    bf16* Qb  = (bf16*)(ws + 16*MB);
    bf16* Kb  = (bf16*)(ws + 32*MB);
    bf16* Vtb = (bf16*)(ws + 48*MB);
    bf16* Wqb = (bf16*)(ws + 64*MB);
    bf16* Wkb = (bf16*)(ws + 72*MB);
    bf16* Wvb = (bf16*)(ws + 80*MB);
    bf16* Wob = (bf16*)(ws + 88*MB);
    bf16* Ctx = Xb;

    int n4w = (DIM*DIM) / 4;
    cast6<<<dim3(n4w/256, 6), 256, 0, stream>>>(x, wq, wk, wv, wo,
                                                Xb, Wqb, Wkb, Wvb, Wob, n4w);

    const float qscale = 0.08838834764831845f * 1.4426950408889634f;  // 1/sqrt(128)*log2(e)
    gemm_qk<<<dim3(8, 16, 2), 512, 0, stream>>>(
        Xb, Wqb, Wkb, bq, bk, Qb, Kb, qscale);

    gemm_v<<<dim3(DIM/BN, MTOT/BM), 512, 0, stream>>>(Xb, Wvb, bv, Vtb);

    attn<<<dim3(QLEN/64, BS*H), 256, 0, stream>>>(Qb, Kb, Vtb, mask, Ctx);

    gemm_out<<<dim3(DIM/BN, MTOT/BM), 512, 0, stream>>>(Ctx, Wob, bo, (float*)d_out);
}

// Round 6
// 391.655 us; speedup vs baseline: 1.0284x; 1.0284x over previous
//
#include <hip/hip_runtime.h>
#include <hip/hip_bf16.h>

#define BS 2
#define QLEN 2048
#define DIM 2048
#define H 16
#define DH 128
#define MTOT (BS*QLEN)

#define BM 256
#define BN 128
#define BK 64
#define NT (DIM/BK)   // 32 K-tiles

typedef __hip_bfloat16 bf16;
using f32x4 = __attribute__((ext_vector_type(4))) float;
using s16x8 = __attribute__((ext_vector_type(8))) short;

__device__ inline void gload_lds16(const bf16* g, bf16* l) {
    __builtin_amdgcn_global_load_lds(
        (const __attribute__((address_space(1))) void*)g,
        (__attribute__((address_space(3))) void*)l,
        16, 0, 0);
}

// ---------------- fp32 -> bf16 cast: 6 slices in one dispatch ----------------
__global__ __launch_bounds__(256) void cast6(
    const float* __restrict__ x,
    const float* __restrict__ w0, const float* __restrict__ w1,
    const float* __restrict__ w2, const float* __restrict__ w3,
    bf16* xo, bf16* o0, bf16* o1, bf16* o2, bf16* o3, int n4)
{
    const float* in; bf16* out;
    switch (blockIdx.y) {
        case 0:  in = w0; out = o0; break;
        case 1:  in = w1; out = o1; break;
        case 2:  in = w2; out = o2; break;
        case 3:  in = w3; out = o3; break;
        case 4:  in = x;        out = xo;        break;
        default: in = x + 4*(size_t)n4; out = xo + 4*(size_t)n4; break;
    }
    int i = blockIdx.x * 256 + threadIdx.x;
    if (i < n4) {
        float4 v = ((const float4*)in)[i];
        __hip_bfloat162 p0 = __float22bfloat162_rn(make_float2(v.x, v.y));
        __hip_bfloat162 p1 = __float22bfloat162_rn(make_float2(v.z, v.w));
        ((__hip_bfloat162*)out)[2*i]   = p0;
        ((__hip_bfloat162*)out)[2*i+1] = p1;
    }
}

// ---------------- Q/K projection GEMM: 256x256 tile, wave-tile 128x64 ----------------
__global__ __launch_bounds__(512, 2) void gemm_qk(
    const bf16* __restrict__ A,
    const bf16* __restrict__ Wq, const bf16* __restrict__ Wk,
    const float* __restrict__ bq, const float* __restrict__ bk,
    bf16* __restrict__ Qo, bf16* __restrict__ Ko,
    float qscale)
{
    __shared__ __align__(16) bf16 smem[2*256*64*2];   // 128 KB
    bf16* const SA = smem;
    bf16* const SB = smem + 2*256*64;

    const int t = threadIdx.x;
    const int lane = t & 63, w = t >> 6;
    const int row16 = lane & 15, quad = lane >> 4;

    const int sid = (blockIdx.z * 16 + blockIdx.y) * 8 + blockIdx.x;
    const int swz = (sid & 7) * 32 + (sid >> 3);
    const int zz = swz >> 7;                 // 0: Q, 1: K
    const int m0 = ((swz >> 3) & 15) * 256;
    const int n0 = (swz & 7) * 256;
    const int mo = (w >> 2) * 128, no = (w & 3) * 64;

    const bf16*  Bw   = (zz == 0) ? Wq : Wk;
    const float* bias = (zz == 0) ? bq : bk;
    const float  scale = (zz == 0) ? qscale : 1.0f;

    auto stageA_part = [&](int kt, int bufi, int h) {
        bf16* dst = SA + bufi * (256*64);
        #pragma unroll
        for (int i = 0; i < 2; i++) {
            int c = i*512 + t;
            int rp = c >> 3, g = c & 7;
            int row = (rp & 63) + ((rp & 64) << 1) + h*64;
            int src = g ^ (row & 7);
            gload_lds16(A + (size_t)(m0 + row) * DIM + kt + src*8, dst + (row*8 + g)*8);
        }
    };
    auto stageB_half = [&](int kt, int bufi, int h) {
        bf16* dst = SB + bufi * (256*64);
        #pragma unroll
        for (int i = 0; i < 2; i++) {
            int c = i*512 + t;
            int rp = c >> 3, g = c & 7;
            int row = rp + h*128;
            int src = g ^ (row & 7);
            gload_lds16(Bw + (size_t)(n0 + row) * DIM + kt + src*8, dst + (row*8 + g)*8);
        }
    };

    f32x4 acc[8][4];
    #pragma unroll
    for (int i = 0; i < 8; i++)
        #pragma unroll
        for (int j = 0; j < 4; j++)
            acc[i][j] = (f32x4){0.f, 0.f, 0.f, 0.f};

    stageB_half(0, 0, 0); stageB_half(0, 0, 1);
    stageA_part(0, 0, 0); stageA_part(0, 0, 1);
    asm volatile("s_waitcnt vmcnt(0)" ::: "memory");
    __builtin_amdgcn_s_barrier();
    asm volatile("" ::: "memory");

    for (int J = 0; J < NT; ++J) {
        const bf16* Asb = SA + (J & 1) * (256*64);
        const bf16* Bsb = SB + (J & 1) * (256*64);
        const int stbuf = (J + 1) & 1;
        const bool st = (J + 1 < NT);
        s16x8 bfr[4][2];

        #pragma unroll
        for (int p = 0; p < 4; ++p) {
            s16x8 af[2][2];
            #pragma unroll
            for (int i = 0; i < 2; i++)
                #pragma unroll
                for (int kk = 0; kk < 2; kk++)
                    af[i][kk] = *(const s16x8*)&Asb[(mo + (2*p+i)*16 + row16)*64 +
                                                    (((kk*4+quad) ^ (row16&7)))*8];
            if (p == 0) {
                #pragma unroll
                for (int nj = 0; nj < 4; nj++)
                    #pragma unroll
                    for (int kk = 0; kk < 2; kk++)
                        bfr[nj][kk] = *(const s16x8*)&Bsb[(no + nj*16 + row16)*64 +
                                                          (((kk*4+quad) ^ (row16&7)))*8];
            }
            if (st) {
                if      (p == 0) stageB_half((J+1)*BK, stbuf, 0);
                else if (p == 1) stageB_half((J+1)*BK, stbuf, 1);
                else if (p == 2) stageA_part((J+1)*BK, stbuf, 0);
                else             stageA_part((J+1)*BK, stbuf, 1);
            }
            if (p == 1) {
                if (J < NT-1) asm volatile("s_waitcnt vmcnt(4)" ::: "memory");
                else          asm volatile("s_waitcnt vmcnt(0)" ::: "memory");
            }
            if (p == 3 && J < NT-1)
                asm volatile("s_waitcnt vmcnt(2)" ::: "memory");

            asm volatile("" ::: "memory");
            __builtin_amdgcn_s_barrier();
            asm volatile("s_waitcnt lgkmcnt(0)" ::: "memory");
            __builtin_amdgcn_sched_barrier(0);
            __builtin_amdgcn_s_setprio(1);
            #pragma unroll
            for (int kk = 0; kk < 2; kk++)
                #pragma unroll
                for (int i = 0; i < 2; i++)
                    #pragma unroll
                    for (int nj = 0; nj < 4; nj++)
                        acc[2*p+i][nj] = __builtin_amdgcn_mfma_f32_16x16x32_bf16(
                            af[i][kk], bfr[nj][kk], acc[2*p+i][nj], 0, 0, 0);
            __builtin_amdgcn_s_setprio(0);
            if (!(p == 3 && J == NT-1)) {
                asm volatile("" ::: "memory");
                __builtin_amdgcn_s_barrier();
                asm volatile("" ::: "memory");
            }
        }
    }

    bf16* out = (zz == 0) ? Qo : Ko;
    #pragma unroll
    for (int mi = 0; mi < 8; mi++)
        #pragma unroll
        for (int nj = 0; nj < 4; nj++) {
            int n = n0 + no + nj*16 + row16;
            float bv_ = bias[n];
            #pragma unroll
            for (int r = 0; r < 4; r++) {
                int m = m0 + mo + mi*16 + quad*4 + r;
                out[(size_t)m * DIM + n] = __float2bfloat16((acc[mi][nj][r] + bv_) * scale);
            }
        }
}

// ---------------- V projection GEMM (2-phase, V-transposed out) ----------------
__global__ __launch_bounds__(512, 2) void gemm_v(
    const bf16* __restrict__ A, const bf16* __restrict__ B,
    const float* __restrict__ bias, bf16* __restrict__ Vo)
{
    __shared__ __align__(16) bf16 smem[3*BM*BK + 3*BN*BK];
    bf16* const SA = smem;
    bf16* const SB = smem + 3*BM*BK;

    const int t = threadIdx.x;
    const int lane = t & 63, w = t >> 6;
    const int row16 = lane & 15, quad = lane >> 4;
    const int sid = blockIdx.y * gridDim.x + blockIdx.x;
    const int swz = (sid & 7) * 32 + (sid >> 3);
    const int m0 = (swz >> 4) * BM, n0 = (swz & 15) * BN;
    const int mo = (w >> 1) * 64, no = (w & 1) * 64;

    auto stageA = [&](int kt, int bufi) {
        bf16* dst = SA + bufi * (BM*BK);
        #pragma unroll
        for (int i = 0; i < 4; i++) {
            int idx = i*512 + t;
            int row = idx >> 3, g = idx & 7;
            int src = g ^ (row & 7);
            gload_lds16(A + (size_t)(m0 + row) * DIM + kt + src*8, dst + idx*8);
        }
    };
    auto stageB = [&](int kt, int bufi) {
        bf16* dst = SB + bufi * (BN*BK);
        #pragma unroll
        for (int i = 0; i < 2; i++) {
            int idx = i*512 + t;
            int row = idx >> 3, g = idx & 7;
            int src = g ^ (row & 7);
            gload_lds16(B + (size_t)(n0 + row) * DIM + kt + src*8, dst + idx*8);
        }
    };

    f32x4 acc[4][4];
    for (int i = 0; i < 4; i++)
        for (int j = 0; j < 4; j++)
            acc[i][j] = (f32x4){0.f, 0.f, 0.f, 0.f};

    stageA(0,    0); stageB(0,    0);
    stageA(BK,   1); stageB(BK,   1);
    stageA(2*BK, 2); stageB(2*BK, 2);
    asm volatile("s_waitcnt vmcnt(12)" ::: "memory");
    __builtin_amdgcn_s_barrier();
    asm volatile("" ::: "memory");

    int buf = 0;
    for (int J = 0; J < NT; ++J) {
        const bf16* Asb = SA + buf * (BM*BK);
        const bf16* Bsb = SB + buf * (BN*BK);

        s16x8 af0[4], bf0[4];
        #pragma unroll
        for (int mt = 0; mt < 4; mt++)
            af0[mt] = *(const s16x8*)&Asb[(mo + mt*16 + row16)*BK + ((quad ^ (row16&7)))*8];
        #pragma unroll
        for (int nt = 0; nt < 4; nt++)
            bf0[nt] = *(const s16x8*)&Bsb[(no + nt*16 + row16)*BK + ((quad ^ (row16&7)))*8];
        if (J >= 1 && J + 2 < NT) {
            int sl = (buf == 0) ? 2 : buf - 1;
            stageA((J+2)*BK, sl); stageB((J+2)*BK, sl);
        }
        asm volatile("" ::: "memory");
        __builtin_amdgcn_s_barrier();
        asm volatile("s_waitcnt lgkmcnt(0)" ::: "memory");
        __builtin_amdgcn_sched_barrier(0);
        __builtin_amdgcn_s_setprio(1);
        #pragma unroll
        for (int mt = 0; mt < 4; mt++)
            #pragma unroll
            for (int nt = 0; nt < 4; nt++)
                acc[mt][nt] = __builtin_amdgcn_mfma_f32_16x16x32_bf16(
                    af0[mt], bf0[nt], acc[mt][nt], 0, 0, 0);
        __builtin_amdgcn_s_setprio(0);
        asm volatile("" ::: "memory");
        __builtin_amdgcn_s_barrier();
        asm volatile("" ::: "memory");

        s16x8 af1[4], bf1[4];
        #pragma unroll
        for (int mt = 0; mt < 4; mt++)
            af1[mt] = *(const s16x8*)&Asb[(mo + mt*16 + row16)*BK + (((4+quad) ^ (row16&7)))*8];
        #pragma unroll
        for (int nt = 0; nt < 4; nt++)
            bf1[nt] = *(const s16x8*)&Bsb[(no + nt*16 + row16)*BK + (((4+quad) ^ (row16&7)))*8];
        asm volatile("" ::: "memory");
        __builtin_amdgcn_s_barrier();
        asm volatile("s_waitcnt lgkmcnt(0)" ::: "memory");
        __builtin_amdgcn_sched_barrier(0);
        __builtin_amdgcn_s_setprio(1);
        #pragma unroll
        for (int mt = 0; mt < 4; mt++)
            #pragma unroll
            for (int nt = 0; nt < 4; nt++)
                acc[mt][nt] = __builtin_amdgcn_mfma_f32_16x16x32_bf16(
                    af1[mt], bf1[nt], acc[mt][nt], 0, 0, 0);
        __builtin_amdgcn_s_setprio(0);
        if (J < NT-2)
            asm volatile("s_waitcnt vmcnt(6)" ::: "memory");
        else if (J == NT-2)
            asm volatile("s_waitcnt vmcnt(0)" ::: "memory");
        if (J < NT-1) {
            asm volatile("" ::: "memory");
            __builtin_amdgcn_s_barrier();
            asm volatile("" ::: "memory");
        }
        buf = (buf == 2) ? 0 : buf + 1;
    }

    __syncthreads();
    bf16* Ts = smem;                 // 128 x 264
    for (int mt = 0; mt < 4; mt++)
        for (int nt = 0; nt < 4; nt++) {
            int nn = no + nt*16 + row16;
            float bv_ = bias[n0 + nn];
            for (int r = 0; r < 4; r++) {
                int mm = mo + mt*16 + quad*4 + r;
                Ts[nn*264 + mm] = __float2bfloat16(acc[mt][nt][r] + bv_);
            }
        }
    __syncthreads();
    const int b = m0 >> 11, q0b = m0 & 2047;
    #pragma unroll
    for (int i = 0; i < 8; i++) {
        int chunk = i*512 + t;
        int row = chunk >> 5;
        int c = chunk & 31;
        s16x8 val = *(const s16x8*)&Ts[row*264 + c*8];
        *(s16x8*)(Vo + ((size_t)(b*DIM + n0 + row))*QLEN + q0b + c*8) = val;
    }
}

// ---------------- O-projection GEMM (2-phase), fp32 out ----------------
__global__ __launch_bounds__(512, 2) void gemm_out(
    const bf16* __restrict__ A, const bf16* __restrict__ B,
    const float* __restrict__ bias, float* __restrict__ out)
{
    __shared__ __align__(16) bf16 smem[3*BM*BK + 3*BN*BK];
    bf16* const SA = smem;
    bf16* const SB = smem + 3*BM*BK;

    const int t = threadIdx.x;
    const int lane = t & 63, w = t >> 6;
    const int row16 = lane & 15, quad = lane >> 4;
    const int sid = blockIdx.y * gridDim.x + blockIdx.x;
    const int swz = (sid & 7) * 32 + (sid >> 3);
    const int m0 = (swz >> 4) * BM, n0 = (swz & 15) * BN;
    const int mo = (w >> 1) * 64, no = (w & 1) * 64;

    auto stageA = [&](int kt, int bufi) {
        bf16* dst = SA + bufi * (BM*BK);
        #pragma unroll
        for (int i = 0; i < 4; i++) {
            int idx = i*512 + t;
            int row = idx >> 3, g = idx & 7;
            int src = g ^ (row & 7);
            gload_lds16(A + (size_t)(m0 + row) * DIM + kt + src*8, dst + idx*8);
        }
    };
    auto stageB = [&](int kt, int bufi) {
        bf16* dst = SB + bufi * (BN*BK);
        #pragma unroll
        for (int i = 0; i < 2; i++) {
            int idx = i*512 + t;
            int row = idx >> 3, g = idx & 7;
            int src = g ^ (row & 7);
            gload_lds16(B + (size_t)(n0 + row) * DIM + kt + src*8, dst + idx*8);
        }
    };

    f32x4 acc[4][4];
    for (int i = 0; i < 4; i++)
        for (int j = 0; j < 4; j++)
            acc[i][j] = (f32x4){0.f, 0.f, 0.f, 0.f};

    stageA(0,    0); stageB(0,    0);
    stageA(BK,   1); stageB(BK,   1);
    stageA(2*BK, 2); stageB(2*BK, 2);
    asm volatile("s_waitcnt vmcnt(12)" ::: "memory");
    __builtin_amdgcn_s_barrier();
    asm volatile("" ::: "memory");

    int buf = 0;
    for (int J = 0; J < NT; ++J) {
        const bf16* Asb = SA + buf * (BM*BK);
        const bf16* Bsb = SB + buf * (BN*BK);

        s16x8 af0[4], bf0[4];
        #pragma unroll
        for (int mt = 0; mt < 4; mt++)
            af0[mt] = *(const s16x8*)&Asb[(mo + mt*16 + row16)*BK + ((quad ^ (row16&7)))*8];
        #pragma unroll
        for (int nt = 0; nt < 4; nt++)
            bf0[nt] = *(const s16x8*)&Bsb[(no + nt*16 + row16)*BK + ((quad ^ (row16&7)))*8];
        if (J >= 1 && J + 2 < NT) {
            int sl = (buf == 0) ? 2 : buf - 1;
            stageA((J+2)*BK, sl); stageB((J+2)*BK, sl);
        }
        asm volatile("" ::: "memory");
        __builtin_amdgcn_s_barrier();
        asm volatile("s_waitcnt lgkmcnt(0)" ::: "memory");
        __builtin_amdgcn_sched_barrier(0);
        __builtin_amdgcn_s_setprio(1);
        #pragma unroll
        for (int mt = 0; mt < 4; mt++)
            #pragma unroll
            for (int nt = 0; nt < 4; nt++)
                acc[mt][nt] = __builtin_amdgcn_mfma_f32_16x16x32_bf16(
                    af0[mt], bf0[nt], acc[mt][nt], 0, 0, 0);
        __builtin_amdgcn_s_setprio(0);
        asm volatile("" ::: "memory");
        __builtin_amdgcn_s_barrier();
        asm volatile("" ::: "memory");

        s16x8 af1[4], bf1[4];
        #pragma unroll
        for (int mt = 0; mt < 4; mt++)
            af1[mt] = *(const s16x8*)&Asb[(mo + mt*16 + row16)*BK + (((4+quad) ^ (row16&7)))*8];
        #pragma unroll
        for (int nt = 0; nt < 4; nt++)
            bf1[nt] = *(const s16x8*)&Bsb[(no + nt*16 + row16)*BK + (((4+quad) ^ (row16&7)))*8];
        asm volatile("" ::: "memory");
        __builtin_amdgcn_s_barrier();
        asm volatile("s_waitcnt lgkmcnt(0)" ::: "memory");
        __builtin_amdgcn_sched_barrier(0);
        __builtin_amdgcn_s_setprio(1);
        #pragma unroll
        for (int mt = 0; mt < 4; mt++)
            #pragma unroll
            for (int nt = 0; nt < 4; nt++)
                acc[mt][nt] = __builtin_amdgcn_mfma_f32_16x16x32_bf16(
                    af1[mt], bf1[nt], acc[mt][nt], 0, 0, 0);
        __builtin_amdgcn_s_setprio(0);
        if (J < NT-2)
            asm volatile("s_waitcnt vmcnt(6)" ::: "memory");
        else if (J == NT-2)
            asm volatile("s_waitcnt vmcnt(0)" ::: "memory");
        if (J < NT-1) {
            asm volatile("" ::: "memory");
            __builtin_amdgcn_s_barrier();
            asm volatile("" ::: "memory");
        }
        buf = (buf == 2) ? 0 : buf + 1;
    }

    for (int mt = 0; mt < 4; mt++)
        for (int nt = 0; nt < 4; nt++) {
            int n = n0 + no + nt*16 + row16;
            float bv_ = bias[n];
            for (int r = 0; r < 4; r++) {
                int m = m0 + mo + mt*16 + quad*4 + r;
                out[(size_t)m * DIM + n] = acc[mt][nt][r] + bv_;
            }
        }
}

// ---------------- flash attention: QBLK=128, dbuf K AND V, single counted vmcnt ----------------
// 4 waves x 32 q-rows (qs=2). LDS 80KB: Ks[2] 32K + Vs[2] 32K + Pl 16K -> 2 blocks/CU.
// Per tile: [bar: compute(it-1) done, buf^1 free][stage K,V(it+1)->buf^1 (8 gloads)]
//           [vmcnt(8): tile it landed, issued a FULL TILE earlier][bar][QK][softmax->Pl[w]]
//           [lgkm0 (own Pl only; per-wave)][PV]. No vmcnt(0) until last tile.
__global__ __launch_bounds__(256, 2) void attn(
    const bf16* __restrict__ Q, const bf16* __restrict__ Kb,
    const bf16* __restrict__ Vt, const int* __restrict__ mask,
    bf16* __restrict__ Ctx)
{
    __shared__ __align__(16) bf16 Ks[2][64*128];  // 32 KB
    __shared__ __align__(16) bf16 Vs[2][128*64];  // 32 KB
    __shared__ __align__(16) bf16 Pl[4][32*64];   // 16 KB (swizzled, per-wave)

    const int t = threadIdx.x, w = t >> 6, lane = t & 63;
    const int row16 = lane & 15, quad = lane >> 4;
    // XCD swizzle: 512 blocks, 64 per XCD = 4 bh-groups x 16 q-tiles intact
    const int sid = blockIdx.y * gridDim.x + blockIdx.x;
    const int swz = (sid & 7) * 64 + (sid >> 3);
    const int bh = swz >> 4, b = bh >> 4, h = bh & 15;
    const int q0 = (swz & 15) * 128 + w * 32;

    s16x8 qf[2][4];
    for (int qs = 0; qs < 2; qs++) {
        const bf16* qp = Q + (size_t)(b*QLEN + q0 + qs*16 + row16) * DIM + h*DH;
        for (int ks = 0; ks < 4; ks++)
            qf[qs][ks] = *(const s16x8*)(qp + ks*32 + quad*8);
    }

    f32x4 o[2][8];
    for (int qs = 0; qs < 2; qs++)
        for (int i = 0; i < 8; i++) o[qs][i] = (f32x4){0.f, 0.f, 0.f, 0.f};
    float lsum[2][4] = {{0.f,0.f,0.f,0.f},{0.f,0.f,0.f,0.f}};
    const int* mrow = mask + b * QLEN;

    const bf16* Kbase = Kb + (size_t)b*QLEN*DIM + h*DH;
    const bf16* Vbase = Vt + ((size_t)b*DIM + h*DH) * QLEN;

    auto stageK = [&](int kt, int bi) {
        #pragma unroll
        for (int i = 0; i < 4; i++) {
            int idx = i*256 + t;
            int kr = idx >> 4, kc = idx & 15;
            int kg = kc ^ (kr & 15);
            gload_lds16(Kbase + (size_t)(kt + kr) * DIM + kg*8, &Ks[bi][idx*8]);
        }
    };
    auto stageV = [&](int kt, int bi) {
        #pragma unroll
        for (int i = 0; i < 4; i++) {
            int idx = i*256 + t;
            int vd = idx >> 3, vc = idx & 7;
            int vg = vc ^ (vd & 7);
            gload_lds16(Vbase + (size_t)vd * QLEN + kt + vg*8, &Vs[bi][idx*8]);
        }
    };

    // prologue: tile 0 into buf 0
    stageK(0, 0);
    stageV(0, 0);

    for (int it = 0; it < QLEN/64; it++) {
        const int kt = it * 64, buf = it & 1;

        // ---- all waves done compute(it-1): buf^1 K/V free to overwrite ----
        asm volatile("" ::: "memory");
        __builtin_amdgcn_s_barrier();
        asm volatile("" ::: "memory");

        if (it + 1 < QLEN/64) {
            stageK(kt + 64, buf ^ 1);        // 8 gloads for tile it+1
            stageV(kt + 64, buf ^ 1);
            asm volatile("s_waitcnt vmcnt(8)" ::: "memory");  // tile it (issued a full tile ago) landed
        } else {
            asm volatile("s_waitcnt vmcnt(0)" ::: "memory");  // last tile landed
        }
        asm volatile("" ::: "memory");
        __builtin_amdgcn_s_barrier();        // all waves: tile it resident in Ks/Vs[buf]
        asm volatile("" ::: "memory");

        float mval[4];
        #pragma unroll
        for (int nt = 0; nt < 4; nt++)
            mval[nt] = (mrow[kt + nt*16 + row16] != 0) ? -20.0f : -1e30f;

        // ---- scores from Ks[buf] ----
        f32x4 sc[2][4];
        for (int qs = 0; qs < 2; qs++)
            for (int nt = 0; nt < 4; nt++) sc[qs][nt] = (f32x4){0.f, 0.f, 0.f, 0.f};
        __builtin_amdgcn_s_setprio(1);
        #pragma unroll
        for (int ks = 0; ks < 4; ks++) {
            #pragma unroll
            for (int nt = 0; nt < 4; nt++) {
                int rrow = nt*16 + row16;
                int c = (ks*4 + quad) ^ row16;
                s16x8 kf = *(const s16x8*)&Ks[buf][rrow*128 + c*8];
                sc[0][nt] = __builtin_amdgcn_mfma_f32_16x16x32_bf16(qf[0][ks], kf, sc[0][nt], 0, 0, 0);
                sc[1][nt] = __builtin_amdgcn_mfma_f32_16x16x32_bf16(qf[1][ks], kf, sc[1][nt], 0, 0, 0);
            }
        }
        __builtin_amdgcn_s_setprio(0);

        // ---- softmax numerator: p = exp2(s - 20) -> Pl[w] (per-wave, swizzled) ----
        #pragma unroll
        for (int qs = 0; qs < 2; qs++) {
            #pragma unroll
            for (int r = 0; r < 4; r++) {
                int prow = qs*16 + quad*4 + r;
                float ts = 0.f;
                #pragma unroll
                for (int nt = 0; nt < 4; nt++) {
                    float p = exp2f(sc[qs][nt][r] + mval[nt]);
                    ts += p;
                    int chunk = nt*2 + (row16 >> 3);
                    int slot = chunk ^ (prow & 7);
                    Pl[w][prow*64 + slot*8 + (row16 & 7)] = __float2bfloat16(p);
                }
                lsum[qs][r] += ts;
            }
        }

        // own Pl writes done (Pl[w] is wave-private; no barrier needed)
        asm volatile("s_waitcnt lgkmcnt(0)" ::: "memory");
        __builtin_amdgcn_sched_barrier(0);

        // ---- PV from Vs[buf] ----
        __builtin_amdgcn_s_setprio(1);
        #pragma unroll
        for (int kc = 0; kc < 2; kc++) {
            int pslot0 = ((kc*4 + quad) ^ (row16 & 7));
            s16x8 pf0 = *(const s16x8*)&Pl[w][(0*16 + row16)*64 + pslot0*8];
            s16x8 pf1 = *(const s16x8*)&Pl[w][(1*16 + row16)*64 + pslot0*8];
            #pragma unroll
            for (int nt = 0; nt < 8; nt++) {
                int d = nt*16 + row16;
                int c = (kc*4 + quad) ^ (d & 7);
                s16x8 vf = *(const s16x8*)&Vs[buf][d*64 + c*8];
                o[0][nt] = __builtin_amdgcn_mfma_f32_16x16x32_bf16(pf0, vf, o[0][nt], 0, 0, 0);
                o[1][nt] = __builtin_amdgcn_mfma_f32_16x16x32_bf16(pf1, vf, o[1][nt], 0, 0, 0);
            }
        }
        __builtin_amdgcn_s_setprio(0);
    }

    for (int qs = 0; qs < 2; qs++) {
        float inv[4];
        for (int r = 0; r < 4; r++) {
            float ts = lsum[qs][r];
            ts += __shfl_xor(ts, 1);
            ts += __shfl_xor(ts, 2);
            ts += __shfl_xor(ts, 4);
            ts += __shfl_xor(ts, 8);
            inv[r] = 1.0f / ts;
        }
        for (int nt = 0; nt < 8; nt++)
            for (int r = 0; r < 4; r++) {
                float v = o[qs][nt][r] * inv[r];
                Ctx[(size_t)(b*QLEN + q0 + qs*16 + quad*4 + r) * DIM + h*DH + nt*16 + row16] =
                    __float2bfloat16(v);
            }
    }
}

extern "C" void kernel_launch(void* const* d_in, const int* in_sizes, int n_in,
                              void* d_out, int out_size, void* d_ws, size_t ws_size,
                              hipStream_t stream) {
    const float* x    = (const float*)d_in[0];
    const int*   mask = (const int*)d_in[1];
    const float* wq   = (const float*)d_in[2];
    const float* bq   = (const float*)d_in[3];
    const float* wk   = (const float*)d_in[4];
    const float* bk   = (const float*)d_in[5];
    const float* wv   = (const float*)d_in[6];
    const float* bv   = (const float*)d_in[7];
    const float* wo   = (const float*)d_in[8];
    const float* bo   = (const float*)d_in[9];

    char* ws = (char*)d_ws;
    const size_t MB = 1024 * 1024;
    bf16* Xb  = (bf16*)(ws);             // 16MB, later reused as Ctx
    bf16* Qb  = (bf16*)(ws + 16*MB);
    bf16* Kb  = (bf16*)(ws + 32*MB);
    bf16* Vtb = (bf16*)(ws + 48*MB);
    bf16* Wqb = (bf16*)(ws + 64*MB);
    bf16* Wkb = (bf16*)(ws + 72*MB);
    bf16* Wvb = (bf16*)(ws + 80*MB);
    bf16* Wob = (bf16*)(ws + 88*MB);
    bf16* Ctx = Xb;

    int n4w = (DIM*DIM) / 4;
    cast6<<<dim3(n4w/256, 6), 256, 0, stream>>>(x, wq, wk, wv, wo,
                                                Xb, Wqb, Wkb, Wvb, Wob, n4w);

    const float qscale = 0.08838834764831845f * 1.4426950408889634f;  // 1/sqrt(128)*log2(e)
    gemm_qk<<<dim3(8, 16, 2), 512, 0, stream>>>(
        Xb, Wqb, Wkb, bq, bk, Qb, Kb, qscale);

    gemm_v<<<dim3(DIM/BN, MTOT/BM), 512, 0, stream>>>(Xb, Wvb, bv, Vtb);

    attn<<<dim3(QLEN/128, BS*H), 256, 0, stream>>>(Qb, Kb, Vtb, mask, Ctx);

    gemm_out<<<dim3(DIM/BN, MTOT/BM), 512, 0, stream>>>(Ctx, Wob, bo, (float*)d_out);
}